// Round 4
// baseline (403.048 us; speedup 1.0000x reference)
//
#include <hip/hip_runtime.h>
#include <hip/hip_bf16.h>

// Problem constants
#define N_  32
#define E_  512
#define C_  64
#define O_  128
#define H_  64
#define W_  64
#define CK9 576              // C*3*3
#define M_  (O_*CK9)         // 73728

typedef __bf16 bf16x8 __attribute__((ext_vector_type(8)));
typedef float  f32x4  __attribute__((ext_vector_type(4)));

__device__ inline bf16x8 cvt8(const float* p) {
    f32x4 lo = *reinterpret_cast<const f32x4*>(p);
    f32x4 hi = *reinterpret_cast<const f32x4*>(p + 4);
    bf16x8 r;
    r[0] = (__bf16)lo[0]; r[1] = (__bf16)lo[1]; r[2] = (__bf16)lo[2]; r[3] = (__bf16)lo[3];
    r[4] = (__bf16)hi[0]; r[5] = (__bf16)hi[1]; r[6] = (__bf16)hi[2]; r[7] = (__bf16)hi[3];
    return r;
}

// ---------------------------------------------------------------------------
// Kernel 1: filt_packed[n][o][k'] (bf16), k' = t*64 + c (tap-major) where the
// original c1_w index is m = o*576 + c*9 + t.  MFMA 16x16x32 over E=512.
// (Verified passing in rounds 2-3.)
// ---------------------------------------------------------------------------
__global__ __launch_bounds__(256) void gen_filters(
    const float* __restrict__ emb, const float* __restrict__ w_weight,
    const float* __restrict__ w_bias, __bf16* __restrict__ filt)
{
    int tid  = threadIdx.x;
    int wave = tid >> 6, lane = tid & 63;
    int quad = lane >> 4, l16 = lane & 15;
    int m0 = blockIdx.x * 64 + wave * 16;

    f32x4 acc0 = {0.f,0.f,0.f,0.f};
    f32x4 acc1 = {0.f,0.f,0.f,0.f};

    const float* arow = w_weight + (size_t)(m0 + l16) * E_ + quad * 8;
    const float* b0p  = emb + (size_t)l16 * E_ + quad * 8;
    const float* b1p  = emb + (size_t)(l16 + 16) * E_ + quad * 8;

#pragma unroll
    for (int k0 = 0; k0 < E_; k0 += 32) {
        bf16x8 a  = cvt8(arow + k0);
        bf16x8 b0 = cvt8(b0p + k0);
        bf16x8 b1 = cvt8(b1p + k0);
        acc0 = __builtin_amdgcn_mfma_f32_16x16x32_bf16(a, b0, acc0, 0, 0, 0);
        acc1 = __builtin_amdgcn_mfma_f32_16x16x32_bf16(a, b1, acc1, 0, 0, 0);
    }

#pragma unroll
    for (int r = 0; r < 4; r++) {
        int m = m0 + quad * 4 + r;          // original c1_w column index
        int o = m / 576;
        int rem = m - o * 576;
        int c = rem / 9;
        int t = rem - c * 9;
        size_t base = (size_t)o * 576 + t * 64 + c;   // packed k' order
        float bias = w_bias[m];
        filt[(size_t)l16        * M_ + base] = (__bf16)(acc0[r] + bias);
        filt[(size_t)(l16 + 16) * M_ + base] = (__bf16)(acc1[r] + bias);
    }
}

// ---------------------------------------------------------------------------
// Kernel 2: c1b[n][o] = emb[n] . b_weight[o] + b_bias[o]  (fp32)
// ---------------------------------------------------------------------------
__global__ __launch_bounds__(256) void gen_bias(
    const float* __restrict__ emb, const float* __restrict__ b_weight,
    const float* __restrict__ b_bias, float* __restrict__ c1b)
{
    int t = blockIdx.x * 256 + threadIdx.x;   // 0..4095
    int n = t >> 7, o = t & 127;
    const float* a = emb + (size_t)n * E_;
    const float* b = b_weight + (size_t)o * E_;
    float acc = 0.f;
    for (int e = 0; e < E_; e += 4) {
        f32x4 av = *reinterpret_cast<const f32x4*>(a + e);
        f32x4 bv = *reinterpret_cast<const f32x4*>(b + e);
#pragma unroll
        for (int j = 0; j < 4; j++) acc += av[j] * bv[j];
    }
    c1b[t] = acc + b_bias[o];
}

// ---------------------------------------------------------------------------
// Kernel 3: fused implicit-GEMM conv, v2.
// Block = (n, 128-pixel tile = 2 image rows).
//   C[o][p] = sum_{k'} A[o][k'] * B[k'][p],  k' = t*64+c
// A-frags read DIRECTLY from global filt (147 KB per n -> L2-resident,
// shared by 32 blocks) -- no LDS staging, no per-iter barriers.
// B-frags from a once-staged bf16 image slab [4 rows][66 cols][64 c],
// c-stride 72 (144 B rows: 16B-aligned, banks uniformly distributed).
// 4 waves in 2x2; each computes 64(o) x 64(px) via 4x4 frags of 16x16x32.
// Single __syncthreads() in the whole kernel.
// ---------------------------------------------------------------------------
__global__ __launch_bounds__(256) void conv_gemm(
    const float* __restrict__ img, const __bf16* __restrict__ filt,
    const float* __restrict__ c1b, float* __restrict__ out)
{
    __shared__ __align__(16) __bf16 slab[4 * 66 * 72];   // 38016 B

    int tid  = threadIdx.x;
    int wave = tid >> 6, lane = tid & 63;
    int quad = lane >> 4, l16 = lane & 15;
    int wm = wave & 1, wn = wave >> 1;
    int n  = blockIdx.x >> 5;
    int pt = blockIdx.x & 31;
    int p0 = pt << 7;        // first pixel of tile
    int h0 = pt << 1;        // first image row of tile

    // ---- stage image slab: rows h0-1 .. h0+2, cols w=-1..64, all 64 c ----
    const float* imgn = img + (size_t)n * (C_ * H_ * W_);
    for (int idx = tid; idx < 4 * 66 * 64; idx += 256) {
        int col = idx % 66;           // consecutive tid -> consecutive w (coalesced)
        int rc  = idx / 66;
        int c   = rc & 63;
        int r   = rc >> 6;
        int hh  = h0 - 1 + r;
        int w   = col - 1;
        float v = 0.f;
        if ((unsigned)hh < 64u && (unsigned)w < 64u)
            v = imgn[((size_t)c << 12) + (hh << 6) + w];
        slab[(r * 66 + col) * 72 + c] = (__bf16)v;
    }

    f32x4 acc[4][4];
#pragma unroll
    for (int mi = 0; mi < 4; mi++)
#pragma unroll
        for (int ni = 0; ni < 4; ni++)
            acc[mi][ni] = (f32x4){0.f, 0.f, 0.f, 0.f};

    // Per-lane A base: row (wm*64 + mi*16 + l16), col offset quad*8
    const __bf16* fA = filt + (size_t)n * M_ + (size_t)(wm * 64 + l16) * CK9 + quad * 8;

    __syncthreads();   // slab ready; only barrier in the kernel

#pragma unroll
    for (int k0 = 0; k0 < CK9; k0 += 32) {
        int t  = k0 >> 6;           // tap index 0..8
        int di = t / 3;             // vertical shift 0..2
        int tj = t - di * 3;        // horizontal shift 0..2
        int c0 = ((k0 >> 5) & 1) * 32;

        bf16x8 a[4], b[4];
#pragma unroll
        for (int mi = 0; mi < 4; mi++)
            a[mi] = *reinterpret_cast<const bf16x8*>(fA + (size_t)mi * 16 * CK9 + k0);
#pragma unroll
        for (int ni = 0; ni < 4; ni++) {
            int col = ni * 16 + l16 + tj;        // slab col = w + tj
            int r   = wn + di;                   // slab row
            b[ni] = *reinterpret_cast<const bf16x8*>(
                slab + (r * 66 + col) * 72 + c0 + quad * 8);
        }
#pragma unroll
        for (int mi = 0; mi < 4; mi++)
#pragma unroll
            for (int ni = 0; ni < 4; ni++)
                acc[mi][ni] = __builtin_amdgcn_mfma_f32_16x16x32_bf16(
                    a[mi], b[ni], acc[mi][ni], 0, 0, 0);
    }

    // ---- epilogue: C[o][p] + bias -> out[n][o][p] (fp32) ----
#pragma unroll
    for (int mi = 0; mi < 4; mi++) {
#pragma unroll
        for (int r = 0; r < 4; r++) {
            int o = wm * 64 + mi * 16 + quad * 4 + r;
            float bias = c1b[(n << 7) + o];
            float* op = out + (((size_t)(n << 7) + o) << 12) + p0 + wn * 64 + l16;
#pragma unroll
            for (int ni = 0; ni < 4; ni++)
                op[ni * 16] = acc[mi][ni][r] + bias;
        }
    }
}

// ---------------------------------------------------------------------------
extern "C" void kernel_launch(void* const* d_in, const int* in_sizes, int n_in,
                              void* d_out, int out_size, void* d_ws, size_t ws_size,
                              hipStream_t stream)
{
    (void)in_sizes; (void)n_in; (void)out_size; (void)ws_size;
    const float* emb      = (const float*)d_in[0];
    const float* images   = (const float*)d_in[1];
    const float* w_weight = (const float*)d_in[2];
    const float* w_bias   = (const float*)d_in[3];
    const float* b_weight = (const float*)d_in[4];
    const float* b_bias   = (const float*)d_in[5];
    float* out = (float*)d_out;

    __bf16* filt = (__bf16*)d_ws;                                  // N*M bf16 = 4.72 MB
    float*  c1b  = (float*)((char*)d_ws + (size_t)N_ * M_ * 2);    // N*O fp32 = 16 KB

    gen_filters<<<dim3(M_ / 64), dim3(256), 0, stream>>>(emb, w_weight, w_bias, filt);
    gen_bias<<<dim3(16), dim3(256), 0, stream>>>(emb, b_weight, b_bias, c1b);
    conv_gemm<<<dim3(N_ * 32), dim3(256), 0, stream>>>(images, filt, c1b, out);
}

// Round 5
// 371.217 us; speedup vs baseline: 1.0857x; 1.0857x over previous
//
#include <hip/hip_runtime.h>
#include <hip/hip_bf16.h>

// Problem constants
#define N_  32
#define E_  512
#define C_  64
#define O_  128
#define H_  64
#define W_  64
#define CK9 576              // C*3*3
#define M_  (O_*CK9)         // 73728

typedef __bf16 bf16x8 __attribute__((ext_vector_type(8)));
typedef float  f32x4  __attribute__((ext_vector_type(4)));

__device__ inline bf16x8 cvt8(const float* p) {
    f32x4 lo = *reinterpret_cast<const f32x4*>(p);
    f32x4 hi = *reinterpret_cast<const f32x4*>(p + 4);
    bf16x8 r;
    r[0] = (__bf16)lo[0]; r[1] = (__bf16)lo[1]; r[2] = (__bf16)lo[2]; r[3] = (__bf16)lo[3];
    r[4] = (__bf16)hi[0]; r[5] = (__bf16)hi[1]; r[6] = (__bf16)hi[2]; r[7] = (__bf16)hi[3];
    return r;
}

// ---------------------------------------------------------------------------
// Kernel 1: filt_packed[n][o][k'] (bf16), k' = t*64 + c (tap-major) where the
// original c1_w index is m = o*576 + c*9 + t.  MFMA 16x16x32 over E=512.
// (Verified passing in rounds 2-4; left untouched this round.)
// ---------------------------------------------------------------------------
__global__ __launch_bounds__(256) void gen_filters(
    const float* __restrict__ emb, const float* __restrict__ w_weight,
    const float* __restrict__ w_bias, __bf16* __restrict__ filt)
{
    int tid  = threadIdx.x;
    int wave = tid >> 6, lane = tid & 63;
    int quad = lane >> 4, l16 = lane & 15;
    int m0 = blockIdx.x * 64 + wave * 16;

    f32x4 acc0 = {0.f,0.f,0.f,0.f};
    f32x4 acc1 = {0.f,0.f,0.f,0.f};

    const float* arow = w_weight + (size_t)(m0 + l16) * E_ + quad * 8;
    const float* b0p  = emb + (size_t)l16 * E_ + quad * 8;
    const float* b1p  = emb + (size_t)(l16 + 16) * E_ + quad * 8;

#pragma unroll
    for (int k0 = 0; k0 < E_; k0 += 32) {
        bf16x8 a  = cvt8(arow + k0);
        bf16x8 b0 = cvt8(b0p + k0);
        bf16x8 b1 = cvt8(b1p + k0);
        acc0 = __builtin_amdgcn_mfma_f32_16x16x32_bf16(a, b0, acc0, 0, 0, 0);
        acc1 = __builtin_amdgcn_mfma_f32_16x16x32_bf16(a, b1, acc1, 0, 0, 0);
    }

#pragma unroll
    for (int r = 0; r < 4; r++) {
        int m = m0 + quad * 4 + r;
        int o = m / 576;
        int rem = m - o * 576;
        int c = rem / 9;
        int t = rem - c * 9;
        size_t base = (size_t)o * 576 + t * 64 + c;   // packed k' order
        float bias = w_bias[m];
        filt[(size_t)l16        * M_ + base] = (__bf16)(acc0[r] + bias);
        filt[(size_t)(l16 + 16) * M_ + base] = (__bf16)(acc1[r] + bias);
    }
}

// ---------------------------------------------------------------------------
// Kernel 2: c1b[n][o] = emb[n] . b_weight[o] + b_bias[o]  (fp32)
// One wave per (n,o): coalesced dwordx4 loads + 64-lane butterfly reduce.
// ---------------------------------------------------------------------------
__global__ __launch_bounds__(256) void gen_bias(
    const float* __restrict__ emb, const float* __restrict__ b_weight,
    const float* __restrict__ b_bias, float* __restrict__ c1b)
{
    int wid  = (blockIdx.x * 256 + threadIdx.x) >> 6;   // 0..4095
    int lane = threadIdx.x & 63;
    int n = wid >> 7, o = wid & 127;
    const float* e = emb + (size_t)n * E_ + lane * 8;
    const float* b = b_weight + (size_t)o * E_ + lane * 8;
    f32x4 e0 = *reinterpret_cast<const f32x4*>(e);
    f32x4 e1 = *reinterpret_cast<const f32x4*>(e + 4);
    f32x4 w0 = *reinterpret_cast<const f32x4*>(b);
    f32x4 w1 = *reinterpret_cast<const f32x4*>(b + 4);
    float s = e0[0]*w0[0] + e0[1]*w0[1] + e0[2]*w0[2] + e0[3]*w0[3]
            + e1[0]*w1[0] + e1[1]*w1[1] + e1[2]*w1[2] + e1[3]*w1[3];
#pragma unroll
    for (int off = 32; off; off >>= 1) s += __shfl_xor(s, off, 64);
    if (lane == 0) c1b[wid] = s + b_bias[o];
}

// ---------------------------------------------------------------------------
// Kernel 3: fused implicit-GEMM conv, v3 = v2 + explicit software pipeline +
// XCD swizzle.
//   C[o][p] = sum_{k'} A[o][k'] * B[k'][p],  k' = t*64+c
// A-frags direct from global filt (4 samples per XCD -> 588 KB, L2-resident
// thanks to the swizzle). B-frags from once-staged bf16 slab. Fragments are
// double-buffered in registers: iter k+1's loads issue before iter k's MFMAs,
// so the waitcnt before each MFMA group is covered by ~600 cyc of MFMA issue.
// ---------------------------------------------------------------------------
__device__ __forceinline__ void load_a(bf16x8* dst, const __bf16* fA, int k0) {
#pragma unroll
    for (int mi = 0; mi < 4; mi++)
        dst[mi] = *reinterpret_cast<const bf16x8*>(fA + (size_t)mi * 16 * CK9 + k0);
}

__device__ __forceinline__ void load_b(bf16x8* dst, const __bf16* slab,
                                       int wn, int l16, int quad, int k0) {
    int t  = k0 >> 6;            // tap 0..8
    int di = t / 3;
    int tj = t - di * 3;
    int c0 = k0 & 32;
#pragma unroll
    for (int ni = 0; ni < 4; ni++) {
        int col = ni * 16 + l16 + tj;
        dst[ni] = *reinterpret_cast<const bf16x8*>(
            slab + ((wn + di) * 66 + col) * 72 + c0 + quad * 8);
    }
}

__global__ __launch_bounds__(256) void conv_gemm(
    const float* __restrict__ img, const __bf16* __restrict__ filt,
    const float* __restrict__ c1b, float* __restrict__ out)
{
    __shared__ __align__(16) __bf16 slab[4 * 66 * 72];   // 38016 B

    int tid  = threadIdx.x;
    int wave = tid >> 6, lane = tid & 63;
    int quad = lane >> 4, l16 = lane & 15;
    int wm = wave & 1, wn = wave >> 1;

    // XCD swizzle: blocks on XCD x (= blk%8) get n in {4x..4x+3} only.
    // blk = x + 8j, j = 4m+r  ->  n = 4x+r, pt = m   (bijective over 1024)
    int blk = blockIdx.x;
    int xcd = blk & 7, jj = blk >> 3;
    int n  = (xcd << 2) + (jj & 3);
    int pt = jj >> 2;
    int p0 = pt << 7;        // first pixel of tile
    int h0 = pt << 1;        // first image row of tile

    // ---- stage image slab: rows h0-1 .. h0+2, cols w=-1..64, all 64 c ----
    const float* imgn = img + (size_t)n * (C_ * H_ * W_);
    for (int idx = tid; idx < 4 * 66 * 64; idx += 256) {
        int col = idx % 66;
        int rc  = idx / 66;
        int c   = rc & 63;
        int r   = rc >> 6;
        int hh  = h0 - 1 + r;
        int w   = col - 1;
        float v = 0.f;
        if ((unsigned)hh < 64u && (unsigned)w < 64u)
            v = imgn[((size_t)c << 12) + (hh << 6) + w];
        slab[(r * 66 + col) * 72 + c] = (__bf16)v;
    }

    f32x4 acc[4][4];
#pragma unroll
    for (int mi = 0; mi < 4; mi++)
#pragma unroll
        for (int ni = 0; ni < 4; ni++)
            acc[mi][ni] = (f32x4){0.f, 0.f, 0.f, 0.f};

    const __bf16* fA = filt + (size_t)n * M_ + (size_t)(wm * 64 + l16) * CK9 + quad * 8;

    __syncthreads();   // slab ready; only barrier in the kernel

    bf16x8 aA[4], bA[4], aB[4], bB[4];
    load_a(aA, fA, 0);
    load_b(bA, slab, wn, l16, quad, 0);

#define MFMA16(av, bv)                                                        \
    {                                                                         \
        _Pragma("unroll")                                                     \
        for (int mi = 0; mi < 4; mi++)                                        \
            _Pragma("unroll")                                                 \
            for (int ni = 0; ni < 4; ni++)                                    \
                acc[mi][ni] = __builtin_amdgcn_mfma_f32_16x16x32_bf16(        \
                    (av)[mi], (bv)[ni], acc[mi][ni], 0, 0, 0);                \
    }

#pragma unroll
    for (int k = 0; k < 18; k += 2) {
        if (k + 1 < 18) {
            load_a(aB, fA, (k + 1) * 32);
            load_b(bB, slab, wn, l16, quad, (k + 1) * 32);
        }
        MFMA16(aA, bA);
        if (k + 2 < 18) {
            load_a(aA, fA, (k + 2) * 32);
            load_b(bA, slab, wn, l16, quad, (k + 2) * 32);
        }
        MFMA16(aB, bB);
    }
#undef MFMA16

    // ---- epilogue: C[o][p] + bias -> out[n][o][p] (fp32) ----
#pragma unroll
    for (int mi = 0; mi < 4; mi++) {
#pragma unroll
        for (int r = 0; r < 4; r++) {
            int o = wm * 64 + mi * 16 + quad * 4 + r;
            float bias = c1b[(n << 7) + o];
            float* op = out + (((size_t)(n << 7) + o) << 12) + p0 + wn * 64 + l16;
#pragma unroll
            for (int ni = 0; ni < 4; ni++)
                op[ni * 16] = acc[mi][ni][r] + bias;
        }
    }
}

// ---------------------------------------------------------------------------
extern "C" void kernel_launch(void* const* d_in, const int* in_sizes, int n_in,
                              void* d_out, int out_size, void* d_ws, size_t ws_size,
                              hipStream_t stream)
{
    (void)in_sizes; (void)n_in; (void)out_size; (void)ws_size;
    const float* emb      = (const float*)d_in[0];
    const float* images   = (const float*)d_in[1];
    const float* w_weight = (const float*)d_in[2];
    const float* w_bias   = (const float*)d_in[3];
    const float* b_weight = (const float*)d_in[4];
    const float* b_bias   = (const float*)d_in[5];
    float* out = (float*)d_out;

    __bf16* filt = (__bf16*)d_ws;                                  // N*M bf16 = 4.72 MB
    float*  c1b  = (float*)((char*)d_ws + (size_t)N_ * M_ * 2);    // N*O fp32 = 16 KB

    gen_filters<<<dim3(M_ / 64), dim3(256), 0, stream>>>(emb, w_weight, w_bias, filt);
    gen_bias<<<dim3(N_ * O_ / 4), dim3(256), 0, stream>>>(emb, b_weight, b_bias, c1b);
    conv_gemm<<<dim3(N_ * 32), dim3(256), 0, stream>>>(images, filt, c1b, out);
}

// Round 6
// 331.216 us; speedup vs baseline: 1.2169x; 1.1208x over previous
//
#include <hip/hip_runtime.h>
#include <hip/hip_bf16.h>

// Problem constants
#define N_  32
#define E_  512
#define C_  64
#define O_  128
#define H_  64
#define W_  64
#define CK9 576              // C*3*3
#define M_  (O_*CK9)         // 73728

typedef __bf16 bf16x8 __attribute__((ext_vector_type(8)));
typedef __bf16 bf16x4 __attribute__((ext_vector_type(4)));
typedef float  f32x4  __attribute__((ext_vector_type(4)));

// ---------------------------------------------------------------------------
// Kernel 1 (v2): filt_packed[n][o][k'] (bf16), k' = t*64 + c, from
// c1_w[n][m] = emb[n] . w_weight[m] + w_bias[m],  m = o*576 + c*9 + t.
// m97-style: emb staged once in LDS (rows padded to 520), w_weight streamed
// through LDS in coalesced 128-B segments. MFMA 16x16x32, 2x2 frags/wave.
// Block tile: 128 m x 32 n x K=512 (16 iters of BK=32). 576 blocks.
// ---------------------------------------------------------------------------
__global__ __launch_bounds__(256) void gen_filters(
    const float* __restrict__ emb, const float* __restrict__ w_weight,
    const float* __restrict__ w_bias, __bf16* __restrict__ filt)
{
    __shared__ __align__(16) __bf16 embS[32 * 520];   // 33280 B
    __shared__ __align__(16) __bf16 wS[128 * 40];     // 10240 B

    int tid  = threadIdx.x;
    int wave = tid >> 6, lane = tid & 63;
    int quad = lane >> 4, l16 = lane & 15;
    int m0 = blockIdx.x * 128;

    // stage emb (32x512 fp32) -> embS bf16, fully coalesced dwordx4
#pragma unroll
    for (int i = 0; i < 16; i++) {
        int idx = (i * 256 + tid) * 4;        // 0..16383 step 4
        int n = idx >> 9, e = idx & 511;
        f32x4 v = *reinterpret_cast<const f32x4*>(emb + n * 512 + e);
        bf16x4 b;
        b[0] = (__bf16)v[0]; b[1] = (__bf16)v[1]; b[2] = (__bf16)v[2]; b[3] = (__bf16)v[3];
        *reinterpret_cast<bf16x4*>(&embS[n * 520 + e]) = b;
    }

    f32x4 acc[2][2];
#pragma unroll
    for (int mi = 0; mi < 2; mi++)
#pragma unroll
        for (int ni = 0; ni < 2; ni++)
            acc[mi][ni] = (f32x4){0.f, 0.f, 0.f, 0.f};

    int sub = tid & 7, rbase = tid >> 3;      // 8 lanes x 16B cover one 128-B row chunk

    for (int kk = 0; kk < 16; kk++) {
        int k0 = kk * 32;
        __syncthreads();   // wS consumed (iter>0); embS ready (iter 0)
#pragma unroll
        for (int q = 0; q < 4; q++) {
            int row = rbase + q * 32;
            f32x4 v = *reinterpret_cast<const f32x4*>(
                w_weight + (size_t)(m0 + row) * 512 + k0 + sub * 4);
            bf16x4 b;
            b[0] = (__bf16)v[0]; b[1] = (__bf16)v[1]; b[2] = (__bf16)v[2]; b[3] = (__bf16)v[3];
            *reinterpret_cast<bf16x4*>(&wS[row * 40 + sub * 4]) = b;
        }
        __syncthreads();

        bf16x8 a0 = *reinterpret_cast<const bf16x8*>(&wS[(wave * 32 + l16) * 40 + quad * 8]);
        bf16x8 a1 = *reinterpret_cast<const bf16x8*>(&wS[(wave * 32 + 16 + l16) * 40 + quad * 8]);
        bf16x8 b0 = *reinterpret_cast<const bf16x8*>(&embS[l16 * 520 + k0 + quad * 8]);
        bf16x8 b1 = *reinterpret_cast<const bf16x8*>(&embS[(16 + l16) * 520 + k0 + quad * 8]);
        acc[0][0] = __builtin_amdgcn_mfma_f32_16x16x32_bf16(a0, b0, acc[0][0], 0, 0, 0);
        acc[0][1] = __builtin_amdgcn_mfma_f32_16x16x32_bf16(a0, b1, acc[0][1], 0, 0, 0);
        acc[1][0] = __builtin_amdgcn_mfma_f32_16x16x32_bf16(a1, b0, acc[1][0], 0, 0, 0);
        acc[1][1] = __builtin_amdgcn_mfma_f32_16x16x32_bf16(a1, b1, acc[1][1], 0, 0, 0);
    }

    // epilogue: D row=quad*4+r -> m, col=l16 -> n; permute m -> packed k'
#pragma unroll
    for (int mi = 0; mi < 2; mi++) {
#pragma unroll
        for (int r = 0; r < 4; r++) {
            int m = m0 + wave * 32 + mi * 16 + quad * 4 + r;
            int o = m / 576;
            int rem = m - o * 576;
            int c = rem / 9;
            int t = rem - c * 9;
            size_t base = (size_t)o * 576 + t * 64 + c;
            float bias = w_bias[m];
#pragma unroll
            for (int ni = 0; ni < 2; ni++) {
                int n = ni * 16 + l16;
                filt[(size_t)n * M_ + base] = (__bf16)(acc[mi][ni][r] + bias);
            }
        }
    }
}

// ---------------------------------------------------------------------------
// Kernel 2: c1b[n][o] = emb[n] . b_weight[o] + b_bias[o]  (fp32)
// One wave per (n,o): coalesced dwordx4 loads + 64-lane butterfly reduce.
// ---------------------------------------------------------------------------
__global__ __launch_bounds__(256) void gen_bias(
    const float* __restrict__ emb, const float* __restrict__ b_weight,
    const float* __restrict__ b_bias, float* __restrict__ c1b)
{
    int wid  = (blockIdx.x * 256 + threadIdx.x) >> 6;   // 0..4095
    int lane = threadIdx.x & 63;
    int n = wid >> 7, o = wid & 127;
    const float* e = emb + (size_t)n * E_ + lane * 8;
    const float* b = b_weight + (size_t)o * E_ + lane * 8;
    f32x4 e0 = *reinterpret_cast<const f32x4*>(e);
    f32x4 e1 = *reinterpret_cast<const f32x4*>(e + 4);
    f32x4 w0 = *reinterpret_cast<const f32x4*>(b);
    f32x4 w1 = *reinterpret_cast<const f32x4*>(b + 4);
    float s = e0[0]*w0[0] + e0[1]*w0[1] + e0[2]*w0[2] + e0[3]*w0[3]
            + e1[0]*w1[0] + e1[1]*w1[1] + e1[2]*w1[2] + e1[3]*w1[3];
#pragma unroll
    for (int off = 32; off; off >>= 1) s += __shfl_xor(s, off, 64);
    if (lane == 0) c1b[wid] = s + b_bias[o];
}

// ---------------------------------------------------------------------------
// Kernel 3 (v4): fused implicit-GEMM conv, A-in-registers.
// Block = (n, strip of 2 pixel-tiles); 512 blocks x 256 thr (4 waves).
// Each wave: o-tile 32 (wave*32), px-tile 128 (whole pt).
// Per pt: [sync][stage slab vectorized][sync] then 2 K-halves:
//   load A-half (32o x 288k -> 72 VGPR) in one L2 burst, then 9 iters of
//   pure ds_read_b128 + 16 MFMA -- no barriers, no global loads in K-loop.
// Slab: [4 rows][66 cols][64 c + pad8], c innermost (stride 72 elems = 144 B).
// Halo cols 0/65 map to w=-1/64 -> always zero (written as constants).
// ---------------------------------------------------------------------------
__global__ __launch_bounds__(256) void conv_gemm(
    const float* __restrict__ img, const __bf16* __restrict__ filt,
    const float* __restrict__ c1b, float* __restrict__ out)
{
    __shared__ __align__(16) __bf16 slab[4 * 66 * 72];   // 38016 B

    int tid  = threadIdx.x;
    int wave = tid >> 6, lane = tid & 63;
    int quad = lane >> 4, l16 = lane & 15;

    // XCD swizzle: XCD x serves n in {4x..4x+3} only (filt slice stays in L2)
    int blk = blockIdx.x;
    int n     = ((blk & 7) << 2) + ((blk >> 3) & 3);
    int strip = blk >> 5;                     // 0..15

    const float* imgn = img + (size_t)n * (C_ * H_ * W_);
    const __bf16* fBase = filt + (size_t)n * M_ + (size_t)(wave * 32 + l16) * CK9 + quad * 8;

    for (int pt2 = 0; pt2 < 2; pt2++) {
        int pt = strip * 2 + pt2;
        int h0 = pt * 2;

        __syncthreads();   // prior pt's slab reads complete (no-op first iter)

        // ---- stage slab: vector part (w = 0..63, all r, all c) ----
#pragma unroll
        for (int i = 0; i < 16; i++) {
            int idx = i * 256 + tid;          // 0..4095
            int wq  = (idx & 15) * 4;
            int rc  = idx >> 4;               // 0..255
            int r = rc >> 6, c = rc & 63;
            int hh = h0 - 1 + r;
            f32x4 v = {0.f, 0.f, 0.f, 0.f};
            if ((unsigned)hh < 64u)
                v = *reinterpret_cast<const f32x4*>(imgn + ((size_t)c << 12) + (hh << 6) + wq);
            __bf16* d = &slab[(r * 66 + wq + 1) * 72 + c];
            d[0]   = (__bf16)v[0];
            d[72]  = (__bf16)v[1];
            d[144] = (__bf16)v[2];
            d[216] = (__bf16)v[3];
        }
        // ---- halo cols 0 (w=-1) and 65 (w=64): always zero padding ----
#pragma unroll
        for (int idx = tid; idx < 512; idx += 256) {
            int cc = idx & 63, rj = idx >> 6;         // rj 0..7
            int r = rj >> 1, col = (rj & 1) * 65;
            slab[(r * 66 + col) * 72 + cc] = (__bf16)0.f;
        }
        __syncthreads();

        f32x4 acc[2][8];
#pragma unroll
        for (int mi = 0; mi < 2; mi++)
#pragma unroll
            for (int ni = 0; ni < 8; ni++)
                acc[mi][ni] = (f32x4){0.f, 0.f, 0.f, 0.f};

#pragma unroll
        for (int kh = 0; kh < 2; kh++) {
            // A-half burst: 18 dwordx4 from L2, independent
            bf16x8 aR[2][9];
#pragma unroll
            for (int mi = 0; mi < 2; mi++)
#pragma unroll
                for (int t9 = 0; t9 < 9; t9++)
                    aR[mi][t9] = *reinterpret_cast<const bf16x8*>(
                        fBase + (size_t)mi * 16 * CK9 + kh * 288 + t9 * 32);

#pragma unroll
            for (int t9 = 0; t9 < 9; t9++) {
                int kk = kh * 9 + t9;         // 0..17
                int k0 = kk * 32;
                int t  = k0 >> 6;             // tap 0..8
                int di = t / 3;
                int tj = t - 3 * di;
                int c0 = k0 & 32;

                bf16x8 b[8];
#pragma unroll
                for (int ni = 0; ni < 8; ni++) {
                    int lh = ni >> 2;                   // local out-row 0/1
                    int w  = (ni & 3) * 16 + l16;       // 0..63
                    b[ni] = *reinterpret_cast<const bf16x8*>(
                        &slab[((lh + di) * 66 + w + tj) * 72 + c0 + quad * 8]);
                }
#pragma unroll
                for (int mi = 0; mi < 2; mi++)
#pragma unroll
                    for (int ni = 0; ni < 8; ni++)
                        acc[mi][ni] = __builtin_amdgcn_mfma_f32_16x16x32_bf16(
                            aR[mi][t9], b[ni], acc[mi][ni], 0, 0, 0);
            }
        }

        // ---- epilogue: C[o][px] + bias -> out[n][o][pt*128 + px] ----
#pragma unroll
        for (int mi = 0; mi < 2; mi++) {
#pragma unroll
            for (int r = 0; r < 4; r++) {
                int o = wave * 32 + mi * 16 + quad * 4 + r;
                float bias = c1b[(n << 7) + o];
                float* op = out + (((size_t)(n << 7) + o) << 12) + (pt << 7);
#pragma unroll
                for (int ni = 0; ni < 8; ni++)
                    op[(ni >> 2) * 64 + (ni & 3) * 16 + l16] = acc[mi][ni][r] + bias;
            }
        }
    }
}

// ---------------------------------------------------------------------------
extern "C" void kernel_launch(void* const* d_in, const int* in_sizes, int n_in,
                              void* d_out, int out_size, void* d_ws, size_t ws_size,
                              hipStream_t stream)
{
    (void)in_sizes; (void)n_in; (void)out_size; (void)ws_size;
    const float* emb      = (const float*)d_in[0];
    const float* images   = (const float*)d_in[1];
    const float* w_weight = (const float*)d_in[2];
    const float* w_bias   = (const float*)d_in[3];
    const float* b_weight = (const float*)d_in[4];
    const float* b_bias   = (const float*)d_in[5];
    float* out = (float*)d_out;

    __bf16* filt = (__bf16*)d_ws;                                  // N*M bf16 = 4.72 MB
    float*  c1b  = (float*)((char*)d_ws + (size_t)N_ * M_ * 2);    // N*O fp32 = 16 KB

    gen_filters<<<dim3(M_ / 128), dim3(256), 0, stream>>>(emb, w_weight, w_bias, filt);
    gen_bias<<<dim3(N_ * O_ / 4), dim3(256), 0, stream>>>(emb, b_weight, b_bias, c1b);
    conv_gemm<<<dim3(512), dim3(256), 0, stream>>>(images, filt, c1b, out);
}